// Round 11
// baseline (267.502 us; speedup 1.0000x reference)
//
#include <hip/hip_runtime.h>
#include <hip/hip_bf16.h>

// Problem dims
#define B_ 16
#define L_ 2048
#define DF 512
#define H_ 8
#define DH 512
#define U_ 512

typedef unsigned short u16;
typedef __attribute__((ext_vector_type(8))) short bf16x8;
typedef __attribute__((ext_vector_type(4))) float f32x4;

__device__ __forceinline__ u16 f2bf(float x) {
  __hip_bfloat16 h = __float2bfloat16(x);
  u16 u;
  __builtin_memcpy(&u, &h, 2);
  return u;
}

__device__ __forceinline__ float bf2f(u16 u) {
  unsigned x = ((unsigned)u) << 16;
  float f;
  __builtin_memcpy(&f, &x, 4);
  return f;
}

__device__ __forceinline__ void load_lds16(const void* g, void* l) {
  __builtin_amdgcn_global_load_lds(
      (const __attribute__((address_space(1))) void*)g,
      (__attribute__((address_space(3))) void*)l, 16, 0, 0);
}

// tanh(x) = 1 - 2/(1+e^{2x}); exact at +-inf, ~1e-6 abs err.
__device__ __forceinline__ float fast_tanh2(float x) {
  float e = __expf(2.f * x);
  return 1.f - __fdividef(2.f, e + 1.f);
}

// ---------------------------------------------------------------------------
// Merged prep kernel:
//  blocks [0, 16384): features fp32 -> bf16 [B,L,DF], 4 elems/thread
//  blocks [16384, 18432): W1 [H,DF,U] -> W1T [H,U,DF] bf16 (32x32 transpose)
//  blocks [18432, 18560): hproj split-d partials (z = d-chunk of 64)
// ---------------------------------------------------------------------------
__global__ __launch_bounds__(256) void prep_kernel(
    const float* __restrict__ F, u16* __restrict__ Abf,
    const float* __restrict__ W1, u16* __restrict__ W1T,
    const float* __restrict__ hidden, const float* __restrict__ W2,
    float* __restrict__ hpart) {
  __shared__ float t[32][33];
  __shared__ float hs[B_][64];
  if (blockIdx.x < 16384) {
    size_t i = ((size_t)blockIdx.x * 256 + threadIdx.x) * 4;
    float4 v = *(const float4*)(F + i);
    ushort4 o;
    o.x = f2bf(v.x); o.y = f2bf(v.y); o.z = f2bf(v.z); o.w = f2bf(v.w);
    *(ushort4*)(Abf + i) = o;
  } else if (blockIdx.x < 18432) {
    int bid = blockIdx.x - 16384;
    int d0 = (bid & 15) * 32, u0 = ((bid >> 4) & 15) * 32, h = bid >> 8;
    const float* src = W1 + (size_t)h * DF * U_;
    u16* dst = W1T + (size_t)h * U_ * DF;
#pragma unroll
    for (int i = 0; i < 4; ++i) {
      int idx = threadIdx.x + i * 256;
      int r = idx >> 5, c = idx & 31;
      t[r][c] = src[(size_t)(d0 + r) * U_ + u0 + c];
    }
    __syncthreads();
#pragma unroll
    for (int i = 0; i < 4; ++i) {
      int idx = threadIdx.x + i * 256;
      int r = idx >> 5, c = idx & 31;  // r: u index, c: d index
      dst[(size_t)(u0 + r) * DF + d0 + c] = f2bf(t[c][r]);
    }
  } else {
    // hproj partial: 128 blocks = 8 h x 2 uy x 8 dz; 256 threads own one u
    int bid = blockIdx.x - 18432;
    int h = bid & 7, uy = (bid >> 3) & 1, dz = bid >> 4;
    int u = uy * 256 + threadIdx.x;
    int d0 = dz * 64;
    for (int idx = threadIdx.x; idx < B_ * 64; idx += 256) {
      int b = idx >> 6, d = idx & 63;
      hs[b][d] = hidden[(size_t)(b * H_ + h) * DH + d0 + d];
    }
    __syncthreads();
    float acc[B_];
#pragma unroll
    for (int b = 0; b < B_; b++) acc[b] = 0.f;
    const float* w2p = W2 + ((size_t)h * DH + d0) * U_ + u;
    for (int d = 0; d < 64; d++) {
      float w = w2p[(size_t)d * U_];
#pragma unroll
      for (int b = 0; b < B_; b++) acc[b] += hs[b][d] * w;
    }
#pragma unroll
    for (int b = 0; b < B_; b++)
      hpart[(((size_t)dz * B_ + b) * H_ + h) * U_ + u] = acc[b];
  }
}

__global__ __launch_bounds__(256) void hproj_combine_kernel(
    const float* __restrict__ partial, const float* __restrict__ b1,
    const float* __restrict__ b2, float* __restrict__ c) {
  int i = blockIdx.x * 256 + threadIdx.x;  // over B*H*U
  int hu = i & (H_ * U_ - 1);
  float s = b1[hu] + b2[hu];
#pragma unroll
  for (int z = 0; z < 8; z++) s += partial[(size_t)z * B_ * H_ * U_ + i];
  c[i] = s;
}

// ---------------------------------------------------------------------------
// score kernel v11: 256(l) x 512(u) per 1024-thread block, 16 waves (4x4),
// wave = 64l x 64u (acc 64 regs -> 512 B/MFMA LDS reads). Two nc hops of
// 256u (A restaged only 2x -> staged 1.0 GB total; LDS traffic 5.4 GB vs
// R10's 8.5). Flat 16-step loop (no per-nc pipeline drains), BK=64 dbuf
// (128 KB LDS, 1 block/CU but 16 waves = 4/SIMD = R10 occupancy), counted
// vmcnt(4), verified XOR swizzle, cu/vv preloaded (keeps vmcnt math exact),
// tanh epilogues at s=7/15 overlap staging. grid (L/256, B, H), block 1024.
// ---------------------------------------------------------------------------
#define BKV 64

__global__ __launch_bounds__(1024, 4) void score_kernel(
    const u16* __restrict__ Abf, const u16* __restrict__ W1T,
    const float* __restrict__ C, const float* __restrict__ V,
    float* __restrict__ score) {
  int l0 = blockIdx.x * 256;
  int b = blockIdx.y, h = blockIdx.z;
  int tid = threadIdx.x;
  int lane = tid & 63, wid = tid >> 6;  // 16 waves
  int wr = wid >> 2, wc = wid & 3;      // 4 x 4; wave = 64l x 64u
  int rl = lane & 15, q = lane >> 4;
  int khalf = q << 3;

  __shared__ u16 As[2][256 * BKV];  // 32 KB each
  __shared__ u16 Bs[2][256 * BKV];  // 32 KB each
  __shared__ float redsm[4][256];   // 4 KB

  const u16* Fb = Abf + ((size_t)b * L_ + l0) * DF;
  const u16* Wh = W1T + (size_t)h * U_ * DF;
  const float* Cb = C + (size_t)(b * H_ + h) * U_;
  const float* Vh = V + (size_t)h * U_;

  // preload bias/V for both nc hops (16 regs; keeps vmcnt counts exact)
  float cu[2][4], vv[2][4];
#pragma unroll
  for (int nc = 0; nc < 2; ++nc)
#pragma unroll
    for (int n = 0; n < 4; ++n) {
      int col = nc * 256 + wc * 64 + n * 16 + rl;
      cu[nc][n] = Cb[col];
      vv[nc][n] = Vh[col];
    }

  float part[16];
#pragma unroll
  for (int p = 0; p < 16; ++p) part[p] = 0.f;

  f32x4 acc[4][4];
#pragma unroll
  for (int m = 0; m < 4; ++m)
#pragma unroll
    for (int n = 0; n < 4; ++n)
#pragma unroll
      for (int j = 0; j < 4; ++j) acc[m][n][j] = cu[0][n];  // fold +c hop 0

  // Staging: per K-step 2048 16B-chunks per matrix, 2/thread each (4 vmem
  // loads/thread per STAGE). Physical chunk (row, ch) holds logical chunk
  // ch ^ (row&7) (involution; same XOR on the read side -> conflict-free).
#define STAGE(buf, kb, N0)                                                 \
  {                                                                        \
    _Pragma("unroll") for (int i_ = 0; i_ < 2; ++i_) {                     \
      int idx_ = i_ * 1024 + tid;                                          \
      int row_ = idx_ >> 3;                                                \
      int ke_ = ((idx_ & 7) ^ (row_ & 7)) << 3;                            \
      load_lds16(Fb + ((size_t)row_ << 9) + (kb) + ke_,                    \
                 &As[buf][idx_ * 8]);                                      \
      load_lds16(Wh + (((size_t)((N0) + row_)) << 9) + (kb) + ke_,         \
                 &Bs[buf][idx_ * 8]);                                      \
    }                                                                      \
  }

#define COMPUTE(bufi)                                                      \
  {                                                                        \
    _Pragma("unroll") for (int ss = 0; ss < 2; ++ss) {                     \
      bf16x8 bF[4];                                                        \
      _Pragma("unroll") for (int n = 0; n < 4; ++n) {                      \
        int rB = wc * 64 + n * 16 + rl;                                    \
        bF[n] = *(const bf16x8*)&Bs[bufi][(rB << 6) +                      \
                                          ((ss * 32 + khalf) ^             \
                                           ((rB & 7) << 3))];              \
      }                                                                    \
      _Pragma("unroll") for (int m = 0; m < 4; ++m) {                      \
        int rA = wr * 64 + m * 16 + rl;                                    \
        bf16x8 aF = *(const bf16x8*)&As[bufi][(rA << 6) +                  \
                                             ((ss * 32 + khalf) ^          \
                                              ((rA & 7) << 3))];           \
        _Pragma("unroll") for (int n = 0; n < 4; ++n)                      \
          acc[m][n] = __builtin_amdgcn_mfma_f32_16x16x32_bf16(             \
              aF, bF[n], acc[m][n], 0, 0, 0);                              \
      }                                                                    \
    }                                                                      \
  }

  // prologue: stage step 0
  STAGE(0, 0, 0);

  // flat loop: s = nc*8 + kt over 2 nc hops x 8 K-steps; no drains inside
#pragma unroll 1
  for (int s = 0; s < 16; ++s) {
    int cur = s & 1;
    if (s < 15) {
      int kb = ((s + 1) & 7) * BKV;
      int N0n = ((s + 1) >> 3) * 256;
      STAGE(cur ^ 1, kb, N0n);
      asm volatile("s_waitcnt vmcnt(4)" ::: "memory");  // stage(s) landed
    } else {
      asm volatile("s_waitcnt vmcnt(0)" ::: "memory");
    }
    __builtin_amdgcn_s_barrier();
    COMPUTE(cur);
    if (s == 7) {
      // hop-0 epilogue: tanh, *V, partials; reinit acc for hop 1
#pragma unroll
      for (int n = 0; n < 4; ++n)
#pragma unroll
        for (int m = 0; m < 4; ++m)
#pragma unroll
          for (int j = 0; j < 4; ++j) {
            part[m * 4 + j] += fast_tanh2(acc[m][n][j]) * vv[0][n];
            acc[m][n][j] = cu[1][n];
          }
    }
    asm volatile("s_waitcnt lgkmcnt(0)" ::: "memory");
    __builtin_amdgcn_s_barrier();
  }
  // hop-1 epilogue
#pragma unroll
  for (int n = 0; n < 4; ++n)
#pragma unroll
    for (int m = 0; m < 4; ++m)
#pragma unroll
      for (int j = 0; j < 4; ++j)
        part[m * 4 + j] += fast_tanh2(acc[m][n][j]) * vv[1][n];
#undef STAGE
#undef COMPUTE

  // reduce over the 16 u-cols held per 16-lane group (rl)
#pragma unroll
  for (int p = 0; p < 16; ++p) {
    float v = part[p];
    v += __shfl_xor(v, 1, 64);
    v += __shfl_xor(v, 2, 64);
    v += __shfl_xor(v, 4, 64);
    v += __shfl_xor(v, 8, 64);
    part[p] = v;
  }
  __syncthreads();
  if (rl == 0) {
#pragma unroll
    for (int m = 0; m < 4; ++m)
#pragma unroll
      for (int j = 0; j < 4; ++j)
        redsm[wc][wr * 64 + m * 16 + q * 4 + j] = part[m * 4 + j];
  }
  __syncthreads();
  if (tid < 256) {
    float s = redsm[0][tid] + redsm[1][tid] + redsm[2][tid] + redsm[3][tid];
    score[(size_t)(b * H_ + h) * L_ + l0 + tid] = s;
  }
}

// ---------------------------------------------------------------------------
// softmax over L per (b,h) (bV omitted -- uniform over L, cancels);
// writes attn (aliases score -- row LDS-cached first) + aw_out [B,L,H,1].
// ---------------------------------------------------------------------------
__global__ __launch_bounds__(256) void softmax_kernel(
    const float* __restrict__ score, float* __restrict__ attn,
    float* __restrict__ aw_out) {
  int bh = blockIdx.x;
  int b = bh / H_, h = bh % H_;
  const float* s = score + (size_t)bh * L_;
  __shared__ float sv[L_];  // 8 KB
  __shared__ float red[256];

  for (int i = threadIdx.x; i < L_ / 4; i += 256)
    ((float4*)sv)[i] = ((const float4*)s)[i];
  __syncthreads();

  float m = -1e30f;
  for (int l = threadIdx.x; l < L_; l += 256) m = fmaxf(m, sv[l]);
  red[threadIdx.x] = m;
  __syncthreads();
  for (int st = 128; st > 0; st >>= 1) {
    if (threadIdx.x < st)
      red[threadIdx.x] = fmaxf(red[threadIdx.x], red[threadIdx.x + st]);
    __syncthreads();
  }
  m = red[0];
  __syncthreads();

  float sum = 0.f;
  for (int l = threadIdx.x; l < L_; l += 256) sum += __expf(sv[l] - m);
  red[threadIdx.x] = sum;
  __syncthreads();
  for (int st = 128; st > 0; st >>= 1) {
    if (threadIdx.x < st) red[threadIdx.x] += red[threadIdx.x + st];
    __syncthreads();
  }
  float inv = 1.f / red[0];

  for (int l = threadIdx.x; l < L_; l += 256) {
    float a = __expf(sv[l] - m) * inv;
    attn[(size_t)bh * L_ + l] = a;
    aw_out[((size_t)b * L_ + l) * H_ + h] = a;
  }
}

// ---------------------------------------------------------------------------
// context split-L: partial[lz][b,h,d] = sum_{l in chunk lz} attn*F(bf16)
// Reads the bf16 features copy (half the traffic of fp32 F).
// ---------------------------------------------------------------------------
__global__ __launch_bounds__(256) void context_part_kernel(
    const u16* __restrict__ Abf, const float* __restrict__ attn,
    float* __restrict__ partial) {
  int b = blockIdx.x;
  int d0 = blockIdx.y * 64;
  int lz = blockIdx.z;
  int td = threadIdx.x & 63;
  int tl = threadIdx.x >> 6;  // 0..3

  __shared__ float as[H_][256];  // 8 KB
  for (int idx = threadIdx.x; idx < H_ * 256; idx += 256)
    as[idx >> 8][idx & 255] =
        attn[((size_t)b * H_ + (idx >> 8)) * L_ + lz * 256 + (idx & 255)];
  __syncthreads();

  float acc[H_] = {};
  for (int l = tl; l < 256; l += 4) {
    float f = bf2f(Abf[((size_t)b * L_ + lz * 256 + l) * DF + d0 + td]);
#pragma unroll
    for (int h = 0; h < H_; h++) acc[h] += as[h][l] * f;
  }

  __shared__ float red[4][H_][64];  // 8 KB
#pragma unroll
  for (int h = 0; h < H_; h++) red[tl][h][td] = acc[h];
  __syncthreads();
  if (tl == 0) {
#pragma unroll
    for (int h = 0; h < H_; h++) {
      float v = red[0][h][td] + red[1][h][td] + red[2][h][td] + red[3][h][td];
      partial[(size_t)lz * B_ * H_ * DF + ((size_t)b * H_ + h) * DF + d0 + td] =
          v;
    }
  }
}

__global__ __launch_bounds__(256) void context_combine_kernel(
    const float* __restrict__ partial, float* __restrict__ ctx_out) {
  int i = blockIdx.x * 256 + threadIdx.x;  // over B*H*DF
  float s = 0.f;
#pragma unroll
  for (int z = 0; z < 8; z++) s += partial[(size_t)z * B_ * H_ * DF + i];
  ctx_out[i] = s;
}

// ---------------------------------------------------------------------------
extern "C" void kernel_launch(void* const* d_in, const int* in_sizes, int n_in,
                              void* d_out, int out_size, void* d_ws,
                              size_t ws_size, hipStream_t stream) {
  const float* features = (const float*)d_in[0];  // [B,L,Df]
  const float* hidden   = (const float*)d_in[1];  // [B,H,Dh]
  const float* W1       = (const float*)d_in[2];  // [H,Df,U]
  const float* b1       = (const float*)d_in[3];  // [H,U]
  const float* W2       = (const float*)d_in[4];  // [H,Dh,U]
  const float* b2       = (const float*)d_in[5];  // [H,U]
  const float* V        = (const float*)d_in[6];  // [H,U]
  // d_in[7] = bV: uniform over L per (b,h) -> cancels in softmax; unused.

  float* out = (float*)d_out;
  float* ctx_out = out;                 // [B,H,Df]
  float* aw_out  = out + B_ * H_ * DF;  // [B,L,H,1]

  // ws layout (floats): c | score | cpart, then bf16: Abf | W1T
  //  - hproj partials (524288 f) alias score+cpart (786432 f): consumed by
  //    hproj_combine before score/cpart are written.
  //  - attn aliases score (softmax LDS-caches the row before overwriting).
  float* c_buf = (float*)d_ws;
  float* score = c_buf + (size_t)B_ * H_ * U_;
  float* attn  = score;                              // alias (see above)
  float* hpart = score;                              // alias (see above)
  float* cpart = score + (size_t)B_ * H_ * L_;       // 8*B*H*DF floats
  u16* Abf = (u16*)(cpart + (size_t)8 * B_ * H_ * DF);
  u16* W1T = Abf + (size_t)B_ * L_ * DF;

  prep_kernel<<<16384 + 2048 + 128, 256, 0, stream>>>(features, Abf, W1, W1T,
                                                      hidden, W2, hpart);
  hproj_combine_kernel<<<(B_ * H_ * U_) / 256, 256, 0, stream>>>(hpart, b1, b2,
                                                                 c_buf);
  score_kernel<<<dim3(L_ / 256, B_, H_), 1024, 0, stream>>>(Abf, W1T, c_buf, V,
                                                            score);
  softmax_kernel<<<B_ * H_, 256, 0, stream>>>(score, attn, aw_out);
  context_part_kernel<<<dim3(B_, DF / 64, 8), 256, 0, stream>>>(Abf, attn,
                                                                cpart);
  context_combine_kernel<<<(B_ * H_ * DF) / 256, 256, 0, stream>>>(cpart,
                                                                   ctx_out);
}

// Round 12
// 250.959 us; speedup vs baseline: 1.0659x; 1.0659x over previous
//
#include <hip/hip_runtime.h>
#include <hip/hip_bf16.h>

// Problem dims
#define B_ 16
#define L_ 2048
#define DF 512
#define H_ 8
#define DH 512
#define U_ 512

typedef unsigned short u16;
typedef __attribute__((ext_vector_type(8))) short bf16x8;
typedef __attribute__((ext_vector_type(4))) float f32x4;

__device__ __forceinline__ u16 f2bf(float x) {
  __hip_bfloat16 h = __float2bfloat16(x);
  u16 u;
  __builtin_memcpy(&u, &h, 2);
  return u;
}

__device__ __forceinline__ float bf2f(u16 u) {
  unsigned x = ((unsigned)u) << 16;
  float f;
  __builtin_memcpy(&f, &x, 4);
  return f;
}

__device__ __forceinline__ void load_lds16(const void* g, void* l) {
  __builtin_amdgcn_global_load_lds(
      (const __attribute__((address_space(1))) void*)g,
      (__attribute__((address_space(3))) void*)l, 16, 0, 0);
}

// tanh(x) = 1 - 2/(1+e^{2x}); exact at +-inf, ~1e-6 abs err.
__device__ __forceinline__ float fast_tanh2(float x) {
  float e = __expf(2.f * x);
  return 1.f - __fdividef(2.f, e + 1.f);
}

// ---------------------------------------------------------------------------
// Merged prep kernel:
//  blocks [0, 16384): features fp32 -> bf16 [B,L,DF], 4 elems/thread
//  blocks [16384, 18432): W1 [H,DF,U] -> W1T [H,U,DF] bf16 (32x32 transpose)
//  blocks [18432, 18560): hproj split-d partials (z = d-chunk of 64)
// ---------------------------------------------------------------------------
__global__ __launch_bounds__(256) void prep_kernel(
    const float* __restrict__ F, u16* __restrict__ Abf,
    const float* __restrict__ W1, u16* __restrict__ W1T,
    const float* __restrict__ hidden, const float* __restrict__ W2,
    float* __restrict__ hpart) {
  __shared__ float t[32][33];
  __shared__ float hs[B_][64];
  if (blockIdx.x < 16384) {
    size_t i = ((size_t)blockIdx.x * 256 + threadIdx.x) * 4;
    float4 v = *(const float4*)(F + i);
    ushort4 o;
    o.x = f2bf(v.x); o.y = f2bf(v.y); o.z = f2bf(v.z); o.w = f2bf(v.w);
    *(ushort4*)(Abf + i) = o;
  } else if (blockIdx.x < 18432) {
    int bid = blockIdx.x - 16384;
    int d0 = (bid & 15) * 32, u0 = ((bid >> 4) & 15) * 32, h = bid >> 8;
    const float* src = W1 + (size_t)h * DF * U_;
    u16* dst = W1T + (size_t)h * U_ * DF;
#pragma unroll
    for (int i = 0; i < 4; ++i) {
      int idx = threadIdx.x + i * 256;
      int r = idx >> 5, c = idx & 31;
      t[r][c] = src[(size_t)(d0 + r) * U_ + u0 + c];
    }
    __syncthreads();
#pragma unroll
    for (int i = 0; i < 4; ++i) {
      int idx = threadIdx.x + i * 256;
      int r = idx >> 5, c = idx & 31;  // r: u index, c: d index
      dst[(size_t)(u0 + r) * DF + d0 + c] = f2bf(t[c][r]);
    }
  } else {
    // hproj partial: 128 blocks = 8 h x 2 uy x 8 dz; 256 threads own one u
    int bid = blockIdx.x - 18432;
    int h = bid & 7, uy = (bid >> 3) & 1, dz = bid >> 4;
    int u = uy * 256 + threadIdx.x;
    int d0 = dz * 64;
    for (int idx = threadIdx.x; idx < B_ * 64; idx += 256) {
      int b = idx >> 6, d = idx & 63;
      hs[b][d] = hidden[(size_t)(b * H_ + h) * DH + d0 + d];
    }
    __syncthreads();
    float acc[B_];
#pragma unroll
    for (int b = 0; b < B_; b++) acc[b] = 0.f;
    const float* w2p = W2 + ((size_t)h * DH + d0) * U_ + u;
    for (int d = 0; d < 64; d++) {
      float w = w2p[(size_t)d * U_];
#pragma unroll
      for (int b = 0; b < B_; b++) acc[b] += hs[b][d] * w;
    }
#pragma unroll
    for (int b = 0; b < B_; b++)
      hpart[(((size_t)dz * B_ + b) * H_ + h) * U_ + u] = acc[b];
  }
}

__global__ __launch_bounds__(256) void hproj_combine_kernel(
    const float* __restrict__ partial, const float* __restrict__ b1,
    const float* __restrict__ b2, float* __restrict__ c) {
  int i = blockIdx.x * 256 + threadIdx.x;  // over B*H*U
  int hu = i & (H_ * U_ - 1);
  float s = b1[hu] + b2[hu];
#pragma unroll
  for (int z = 0; z < 8; z++) s += partial[(size_t)z * B_ * H_ * U_ + i];
  c[i] = s;
}

// ---------------------------------------------------------------------------
// score kernel v12 (R5's read economy x R10's occupancy):
// 128(l) x 256(u-hop) tile, 8 waves of 64x64 (acc 64 AGPR; 8 ds_read_b128
// per 16 MFMA = 0.5 reads/MFMA), BK=32 double-buffer -> only 50 KB LDS =
// 2 blocks/CU x 8 waves = 4 waves/SIMD. nc=2 outer hops (A staged 2x).
// Counted vmcnt(3) (STAGE = 3 loads/thread), R9-verified BK=32 XOR swizzle,
// per-hop vmcnt(0) fence isolates cu/vv loads from the counted pipeline.
// grid (L/128, B, H), block 512, launch_bounds(512,4): arch-VGPR ~60 + 64
// acc fits the 128 cap (WRITE_SIZE is the spill tripwire).
// ---------------------------------------------------------------------------
#define BKW 32

__global__ __launch_bounds__(512, 4) void score_kernel(
    const u16* __restrict__ Abf, const u16* __restrict__ W1T,
    const float* __restrict__ C, const float* __restrict__ V,
    float* __restrict__ score) {
  int l0 = blockIdx.x * 128;
  int b = blockIdx.y, h = blockIdx.z;
  int tid = threadIdx.x;
  int lane = tid & 63, wid = tid >> 6;  // 8 waves
  int wr = wid >> 2, wc = wid & 3;      // 2 x 4; wave = 64l x 64u
  int rl = lane & 15, q = lane >> 4;

  __shared__ u16 As[2][128 * BKW];  // 8 KB each
  __shared__ u16 Bs[2][256 * BKW];  // 16 KB each
  __shared__ float redsm[4][128];   // 2 KB

  const u16* Fb = Abf + ((size_t)b * L_ + l0) * DF;
  const u16* Wh = W1T + (size_t)h * U_ * DF;
  const float* Cb = C + (size_t)(b * H_ + h) * U_;
  const float* Vh = V + (size_t)h * U_;

  float part[16];
#pragma unroll
  for (int p = 0; p < 16; ++p) part[p] = 0.f;

  // Staging: A = 512 chunks (1/thread), B = 1024 chunks (2/thread); physical
  // chunk (row, ch) holds logical chunk ch ^ ((row>>1)&3) (involution; same
  // XOR on the read side -> conflict-free, R9-verified at BK=32).
#define STAGE(buf, kb, ubase)                                              \
  {                                                                        \
    {                                                                      \
      int row_ = tid >> 2;                                                 \
      int ke_ = ((tid & 3) ^ ((row_ >> 1) & 3)) << 3;                      \
      load_lds16(Fb + ((size_t)row_ << 9) + (kb) + ke_,                    \
                 &As[buf][tid * 8]);                                       \
    }                                                                      \
    _Pragma("unroll") for (int i_ = 0; i_ < 2; ++i_) {                     \
      int idx_ = i_ * 512 + tid;                                           \
      int row_ = idx_ >> 2;                                                \
      int ke_ = ((idx_ & 3) ^ ((row_ >> 1) & 3)) << 3;                     \
      load_lds16(Wh + (((size_t)((ubase) + row_)) << 9) + (kb) + ke_,      \
                 &Bs[buf][idx_ * 8]);                                      \
    }                                                                      \
  }

#define COMPUTE(bufi)                                                      \
  {                                                                        \
    bf16x8 bF[4];                                                          \
    _Pragma("unroll") for (int n = 0; n < 4; ++n) {                        \
      int rB = wc * 64 + n * 16 + rl;                                      \
      bF[n] = *(const bf16x8*)&Bs[bufi][(rB << 5) +                        \
                                        ((q ^ ((rB >> 1) & 3)) << 3)];     \
    }                                                                      \
    _Pragma("unroll") for (int m = 0; m < 4; ++m) {                        \
      int rA = wr * 64 + m * 16 + rl;                                      \
      bf16x8 aF = *(const bf16x8*)&As[bufi][(rA << 5) +                    \
                                           ((q ^ ((rA >> 1) & 3)) << 3)];  \
      _Pragma("unroll") for (int n = 0; n < 4; ++n)                        \
        acc[m][n] = __builtin_amdgcn_mfma_f32_16x16x32_bf16(               \
            aF, bF[n], acc[m][n], 0, 0, 0);                                \
    }                                                                      \
  }

#pragma unroll 1
  for (int nc = 0; nc < 2; ++nc) {
    int ubase = nc * 256;
    // per-hop bias/V for this wave's 64-u slice
    float cu[4], vv[4];
#pragma unroll
    for (int n = 0; n < 4; ++n) {
      int col = ubase + wc * 64 + n * 16 + rl;
      cu[n] = Cb[col];
      vv[n] = Vh[col];
    }
    f32x4 acc[4][4];
#pragma unroll
    for (int m = 0; m < 4; ++m)
#pragma unroll
      for (int n = 0; n < 4; ++n)
#pragma unroll
        for (int j = 0; j < 4; ++j) acc[m][n][j] = cu[n];  // fold +c

    // fence: cu/vv drained so the counted pipeline starts from vmcnt==0
    asm volatile("s_waitcnt vmcnt(0)" ::: "memory");
    STAGE(0, 0, ubase);

#pragma unroll 1
    for (int t = 0; t < 16; ++t) {
      int cur = t & 1;
      if (t < 15) {
        STAGE(cur ^ 1, (t + 1) * BKW, ubase);
        asm volatile("s_waitcnt vmcnt(3)" ::: "memory");  // stage(t) landed
      } else {
        asm volatile("s_waitcnt vmcnt(0)" ::: "memory");
      }
      __builtin_amdgcn_s_barrier();
      COMPUTE(cur);
      asm volatile("s_waitcnt lgkmcnt(0)" ::: "memory");
      __builtin_amdgcn_s_barrier();
    }

    // hop epilogue: tanh, *V, accumulate per-row partials
#pragma unroll
    for (int n = 0; n < 4; ++n)
#pragma unroll
      for (int m = 0; m < 4; ++m)
#pragma unroll
        for (int j = 0; j < 4; ++j)
          part[m * 4 + j] += fast_tanh2(acc[m][n][j]) * vv[n];
  }
#undef STAGE
#undef COMPUTE

  // reduce over the 16 u-cols held per 16-lane group (rl)
#pragma unroll
  for (int p = 0; p < 16; ++p) {
    float v = part[p];
    v += __shfl_xor(v, 1, 64);
    v += __shfl_xor(v, 2, 64);
    v += __shfl_xor(v, 4, 64);
    v += __shfl_xor(v, 8, 64);
    part[p] = v;
  }
  __syncthreads();
  if (rl == 0) {
#pragma unroll
    for (int m = 0; m < 4; ++m)
#pragma unroll
      for (int j = 0; j < 4; ++j)
        redsm[wc][wr * 64 + m * 16 + q * 4 + j] = part[m * 4 + j];
  }
  __syncthreads();
  if (tid < 128) {
    float s = redsm[0][tid] + redsm[1][tid] + redsm[2][tid] + redsm[3][tid];
    score[(size_t)(b * H_ + h) * L_ + l0 + tid] = s;
  }
}

// ---------------------------------------------------------------------------
// softmax over L per (b,h) (bV omitted -- uniform over L, cancels);
// writes attn (aliases score -- row LDS-cached first) + aw_out [B,L,H,1].
// ---------------------------------------------------------------------------
__global__ __launch_bounds__(256) void softmax_kernel(
    const float* __restrict__ score, float* __restrict__ attn,
    float* __restrict__ aw_out) {
  int bh = blockIdx.x;
  int b = bh / H_, h = bh % H_;
  const float* s = score + (size_t)bh * L_;
  __shared__ float sv[L_];  // 8 KB
  __shared__ float red[256];

  for (int i = threadIdx.x; i < L_ / 4; i += 256)
    ((float4*)sv)[i] = ((const float4*)s)[i];
  __syncthreads();

  float m = -1e30f;
  for (int l = threadIdx.x; l < L_; l += 256) m = fmaxf(m, sv[l]);
  red[threadIdx.x] = m;
  __syncthreads();
  for (int st = 128; st > 0; st >>= 1) {
    if (threadIdx.x < st)
      red[threadIdx.x] = fmaxf(red[threadIdx.x], red[threadIdx.x + st]);
    __syncthreads();
  }
  m = red[0];
  __syncthreads();

  float sum = 0.f;
  for (int l = threadIdx.x; l < L_; l += 256) sum += __expf(sv[l] - m);
  red[threadIdx.x] = sum;
  __syncthreads();
  for (int st = 128; st > 0; st >>= 1) {
    if (threadIdx.x < st) red[threadIdx.x] += red[threadIdx.x + st];
    __syncthreads();
  }
  float inv = 1.f / red[0];

  for (int l = threadIdx.x; l < L_; l += 256) {
    float a = __expf(sv[l] - m) * inv;
    attn[(size_t)bh * L_ + l] = a;
    aw_out[((size_t)b * L_ + l) * H_ + h] = a;
  }
}

// ---------------------------------------------------------------------------
// context split-L: partial[lz][b,h,d] = sum_{l in chunk lz} attn*F(bf16)
// Reads the bf16 features copy (half the traffic of fp32 F).
// ---------------------------------------------------------------------------
__global__ __launch_bounds__(256) void context_part_kernel(
    const u16* __restrict__ Abf, const float* __restrict__ attn,
    float* __restrict__ partial) {
  int b = blockIdx.x;
  int d0 = blockIdx.y * 64;
  int lz = blockIdx.z;
  int td = threadIdx.x & 63;
  int tl = threadIdx.x >> 6;  // 0..3

  __shared__ float as[H_][256];  // 8 KB
  for (int idx = threadIdx.x; idx < H_ * 256; idx += 256)
    as[idx >> 8][idx & 255] =
        attn[((size_t)b * H_ + (idx >> 8)) * L_ + lz * 256 + (idx & 255)];
  __syncthreads();

  float acc[H_] = {};
  for (int l = tl; l < 256; l += 4) {
    float f = bf2f(Abf[((size_t)b * L_ + lz * 256 + l) * DF + d0 + td]);
#pragma unroll
    for (int h = 0; h < H_; h++) acc[h] += as[h][l] * f;
  }

  __shared__ float red[4][H_][64];  // 8 KB
#pragma unroll
  for (int h = 0; h < H_; h++) red[tl][h][td] = acc[h];
  __syncthreads();
  if (tl == 0) {
#pragma unroll
    for (int h = 0; h < H_; h++) {
      float v = red[0][h][td] + red[1][h][td] + red[2][h][td] + red[3][h][td];
      partial[(size_t)lz * B_ * H_ * DF + ((size_t)b * H_ + h) * DF + d0 + td] =
          v;
    }
  }
}

__global__ __launch_bounds__(256) void context_combine_kernel(
    const float* __restrict__ partial, float* __restrict__ ctx_out) {
  int i = blockIdx.x * 256 + threadIdx.x;  // over B*H*DF
  float s = 0.f;
#pragma unroll
  for (int z = 0; z < 8; z++) s += partial[(size_t)z * B_ * H_ * DF + i];
  ctx_out[i] = s;
}

// ---------------------------------------------------------------------------
extern "C" void kernel_launch(void* const* d_in, const int* in_sizes, int n_in,
                              void* d_out, int out_size, void* d_ws,
                              size_t ws_size, hipStream_t stream) {
  const float* features = (const float*)d_in[0];  // [B,L,Df]
  const float* hidden   = (const float*)d_in[1];  // [B,H,Dh]
  const float* W1       = (const float*)d_in[2];  // [H,Df,U]
  const float* b1       = (const float*)d_in[3];  // [H,U]
  const float* W2       = (const float*)d_in[4];  // [H,Dh,U]
  const float* b2       = (const float*)d_in[5];  // [H,U]
  const float* V        = (const float*)d_in[6];  // [H,U]
  // d_in[7] = bV: uniform over L per (b,h) -> cancels in softmax; unused.

  float* out = (float*)d_out;
  float* ctx_out = out;                 // [B,H,Df]
  float* aw_out  = out + B_ * H_ * DF;  // [B,L,H,1]

  // ws layout (floats): c | score | cpart, then bf16: Abf | W1T
  //  - hproj partials (524288 f) alias score+cpart (786432 f): consumed by
  //    hproj_combine before score/cpart are written.
  //  - attn aliases score (softmax LDS-caches the row before overwriting).
  float* c_buf = (float*)d_ws;
  float* score = c_buf + (size_t)B_ * H_ * U_;
  float* attn  = score;                              // alias (see above)
  float* hpart = score;                              // alias (see above)
  float* cpart = score + (size_t)B_ * H_ * L_;       // 8*B*H*DF floats
  u16* Abf = (u16*)(cpart + (size_t)8 * B_ * H_ * DF);
  u16* W1T = Abf + (size_t)B_ * L_ * DF;

  prep_kernel<<<16384 + 2048 + 128, 256, 0, stream>>>(features, Abf, W1, W1T,
                                                      hidden, W2, hpart);
  hproj_combine_kernel<<<(B_ * H_ * U_) / 256, 256, 0, stream>>>(hpart, b1, b2,
                                                                 c_buf);
  score_kernel<<<dim3(L_ / 128, B_, H_), 512, 0, stream>>>(Abf, W1T, c_buf, V,
                                                           score);
  softmax_kernel<<<B_ * H_, 256, 0, stream>>>(score, attn, aw_out);
  context_part_kernel<<<dim3(B_, DF / 64, 8), 256, 0, stream>>>(Abf, attn,
                                                                cpart);
  context_combine_kernel<<<(B_ * H_ * DF) / 256, 256, 0, stream>>>(cpart,
                                                                   ctx_out);
}

// Round 13
// 238.995 us; speedup vs baseline: 1.1193x; 1.0501x over previous
//
#include <hip/hip_runtime.h>
#include <hip/hip_bf16.h>

// Problem dims
#define B_ 16
#define L_ 2048
#define DF 512
#define H_ 8
#define DH 512
#define U_ 512

typedef unsigned short u16;
typedef __attribute__((ext_vector_type(8))) short bf16x8;
typedef __attribute__((ext_vector_type(4))) float f32x4;

__device__ __forceinline__ u16 f2bf(float x) {
  __hip_bfloat16 h = __float2bfloat16(x);
  u16 u;
  __builtin_memcpy(&u, &h, 2);
  return u;
}

__device__ __forceinline__ float bf2f(u16 u) {
  unsigned x = ((unsigned)u) << 16;
  float f;
  __builtin_memcpy(&f, &x, 4);
  return f;
}

__device__ __forceinline__ void load_lds16(const void* g, void* l) {
  __builtin_amdgcn_global_load_lds(
      (const __attribute__((address_space(1))) void*)g,
      (__attribute__((address_space(3))) void*)l, 16, 0, 0);
}

// tanh(x) = 1 - 2/(1+e^{2x}); exact at +-inf, ~1e-6 abs err.
__device__ __forceinline__ float fast_tanh2(float x) {
  float e = __expf(2.f * x);
  return 1.f - __fdividef(2.f, e + 1.f);
}

// ---------------------------------------------------------------------------
// Merged prep kernel:
//  blocks [0, 16384): features fp32 -> bf16 [B,L,DF], 4 elems/thread
//  blocks [16384, 18432): W1 [H,DF,U] -> W1T [H,U,DF] bf16 (32x32 transpose)
//  blocks [18432, 18560): hproj split-d partials (z = d-chunk of 64)
// ---------------------------------------------------------------------------
__global__ __launch_bounds__(256) void prep_kernel(
    const float* __restrict__ F, u16* __restrict__ Abf,
    const float* __restrict__ W1, u16* __restrict__ W1T,
    const float* __restrict__ hidden, const float* __restrict__ W2,
    float* __restrict__ hpart) {
  __shared__ float t[32][33];
  __shared__ float hs[B_][64];
  if (blockIdx.x < 16384) {
    size_t i = ((size_t)blockIdx.x * 256 + threadIdx.x) * 4;
    float4 v = *(const float4*)(F + i);
    ushort4 o;
    o.x = f2bf(v.x); o.y = f2bf(v.y); o.z = f2bf(v.z); o.w = f2bf(v.w);
    *(ushort4*)(Abf + i) = o;
  } else if (blockIdx.x < 18432) {
    int bid = blockIdx.x - 16384;
    int d0 = (bid & 15) * 32, u0 = ((bid >> 4) & 15) * 32, h = bid >> 8;
    const float* src = W1 + (size_t)h * DF * U_;
    u16* dst = W1T + (size_t)h * U_ * DF;
#pragma unroll
    for (int i = 0; i < 4; ++i) {
      int idx = threadIdx.x + i * 256;
      int r = idx >> 5, c = idx & 31;
      t[r][c] = src[(size_t)(d0 + r) * U_ + u0 + c];
    }
    __syncthreads();
#pragma unroll
    for (int i = 0; i < 4; ++i) {
      int idx = threadIdx.x + i * 256;
      int r = idx >> 5, c = idx & 31;  // r: u index, c: d index
      dst[(size_t)(u0 + r) * DF + d0 + c] = f2bf(t[c][r]);
    }
  } else {
    // hproj partial: 128 blocks = 8 h x 2 uy x 8 dz; 256 threads own one u
    int bid = blockIdx.x - 18432;
    int h = bid & 7, uy = (bid >> 3) & 1, dz = bid >> 4;
    int u = uy * 256 + threadIdx.x;
    int d0 = dz * 64;
    for (int idx = threadIdx.x; idx < B_ * 64; idx += 256) {
      int b = idx >> 6, d = idx & 63;
      hs[b][d] = hidden[(size_t)(b * H_ + h) * DH + d0 + d];
    }
    __syncthreads();
    float acc[B_];
#pragma unroll
    for (int b = 0; b < B_; b++) acc[b] = 0.f;
    const float* w2p = W2 + ((size_t)h * DH + d0) * U_ + u;
    for (int d = 0; d < 64; d++) {
      float w = w2p[(size_t)d * U_];
#pragma unroll
      for (int b = 0; b < B_; b++) acc[b] += hs[b][d] * w;
    }
#pragma unroll
    for (int b = 0; b < B_; b++)
      hpart[(((size_t)dz * B_ + b) * H_ + h) * U_ + u] = acc[b];
  }
}

__global__ __launch_bounds__(256) void hproj_combine_kernel(
    const float* __restrict__ partial, const float* __restrict__ b1,
    const float* __restrict__ b2, float* __restrict__ c) {
  int i = blockIdx.x * 256 + threadIdx.x;  // over B*H*U
  int hu = i & (H_ * U_ - 1);
  float s = b1[hu] + b2[hu];
#pragma unroll
  for (int z = 0; z < 8; z++) s += partial[(size_t)z * B_ * H_ * U_ + i];
  c[i] = s;
}

// ---------------------------------------------------------------------------
// score kernel v13 (persistent 8-wave, m201 read-economy):
// grid = 256 blocks (1 per CU). Block owns fixed (b, h, u-half 256); loops
// 8 l-items of 256 rows with the staging pipeline LIVE across items (64
// K-tiles deep). 8 waves of 128l x 64u (acc[8][4] = 128 VGPR; LDS reads
// 0.375 KB/MFMA -- 2x better than R10 -> LDS-BW-balance with MFMA).
// Per K-tile: 2 barriers, 64 MFMA/wave, reads 24 x b128, stage halves
// SA0/SB0/SB1/SA1 spread over phases; gates vmcnt(2) at the two closes
// (each staged half gets >=1.5 phases of flight). XCD-clustered mapping:
// the 16 (h,ut) blocks of a given b share one XCD -> A + W1T L2-resident.
// cu (h-proj bias) folded into acc init; loaded once per block.
// ---------------------------------------------------------------------------
__global__ __launch_bounds__(512, 2) void score_kernel(
    const u16* __restrict__ Abf, const u16* __restrict__ W1T,
    const float* __restrict__ C, const float* __restrict__ V,
    float* __restrict__ pscore) {
  int bid = blockIdx.x;  // 0..255; HW round-robins bid&7 across XCDs
  int xcd = bid & 7, slot = bid >> 3;
  int h = slot & 7, ut = (slot >> 3) & 1, mg = slot >> 4;
  int b = xcd * 2 + mg;  // all 16 (h,ut) blocks of this b on one XCD
  int u0 = ut * 256;

  int tid = threadIdx.x;
  int lane = tid & 63, wid = tid >> 6;
  int wr = wid >> 2, wc = wid & 3;  // 2 x 4 waves; wave = 128l x 64u
  int rl = lane & 15, q = lane >> 4;

  __shared__ u16 As[2][256 * 64];  // 32 KB each
  __shared__ u16 Bs[2][256 * 64];  // 32 KB each
  __shared__ float redsm[4][256];  // 4 KB

  const u16* FbB = Abf + (size_t)b * L_ * DF;
  const u16* Wh = W1T + ((size_t)h * U_ + u0) * DF;

  // bias/V once per block (b, h, u-slice all fixed)
  float cu[4], vv[4];
#pragma unroll
  for (int n = 0; n < 4; ++n) {
    int col = u0 + wc * 64 + n * 16 + rl;
    cu[n] = C[(size_t)(b * H_ + h) * U_ + col];
    vv[n] = V[h * U_ + col];
  }
  f32x4 acc[8][4];
#pragma unroll
  for (int m = 0; m < 8; ++m)
#pragma unroll
    for (int n = 0; n < 4; ++n)
#pragma unroll
      for (int j = 0; j < 4; ++j) acc[m][n][j] = cu[n];  // fold +c

  // Staging: half hf (128 rows) of a 256x64 K-tile = 1024 16B chunks =
  // 2 loads/thread. Physical chunk (row, ch) holds logical ch ^ (row&7)
  // (involution; same XOR on read side -> conflict-free b128).
#define SA_(bi, hf, l0v, kb)                                               \
  {                                                                        \
    _Pragma("unroll") for (int i_ = 0; i_ < 2; ++i_) {                     \
      int idx_ = (hf)*1024 + i_ * 512 + tid;                               \
      int row_ = idx_ >> 3;                                                \
      int ke_ = ((idx_ & 7) ^ (row_ & 7)) << 3;                            \
      load_lds16(FbB + (((size_t)((l0v) + row_)) << 9) + (kb) + ke_,       \
                 &As[bi][idx_ * 8]);                                       \
    }                                                                      \
  }
#define SB_(bi, hf, kb)                                                    \
  {                                                                        \
    _Pragma("unroll") for (int i_ = 0; i_ < 2; ++i_) {                     \
      int idx_ = (hf)*1024 + i_ * 512 + tid;                               \
      int row_ = idx_ >> 3;                                                \
      int ke_ = ((idx_ & 7) ^ (row_ & 7)) << 3;                            \
      load_lds16(Wh + (((size_t)row_) << 9) + (kb) + ke_,                  \
                 &Bs[bi][idx_ * 8]);                                       \
    }                                                                      \
  }
#define RD_A(mh, ks, bi)                                                   \
  {                                                                        \
    _Pragma("unroll") for (int mm = 0; mm < 4; ++mm) {                     \
      int rA = wr * 128 + ((mh)*4 + mm) * 16 + rl;                         \
      aF[mm] = *(const bf16x8*)&As[bi][(rA << 6) +                         \
                                       ((((ks)*4 + q) ^ (rA & 7)) << 3)];  \
    }                                                                      \
  }
#define RD_B(ks, bi)                                                       \
  {                                                                        \
    _Pragma("unroll") for (int nn = 0; nn < 4; ++nn) {                     \
      int rB = wc * 64 + nn * 16 + rl;                                     \
      bF[nn] = *(const bf16x8*)&Bs[bi][(rB << 6) +                         \
                                       ((((ks)*4 + q) ^ (rB & 7)) << 3)];  \
    }                                                                      \
  }
#define MMQ(mh)                                                            \
  {                                                                        \
    _Pragma("unroll") for (int mm = 0; mm < 4; ++mm)                       \
    _Pragma("unroll") for (int nn = 0; nn < 4; ++nn)                       \
      acc[(mh)*4 + mm][nn] = __builtin_amdgcn_mfma_f32_16x16x32_bf16(      \
          aF[mm], bF[nn], acc[(mh)*4 + mm][nn], 0, 0, 0);                  \
  }

  // prologue: tile 0 (item 0), all 4 halves; SA1 may stay in flight
  SA_(0, 0, 0, 0);
  SB_(0, 0, 0);
  SB_(0, 1, 0);
  SA_(0, 1, 0, 0);
  asm volatile("s_waitcnt vmcnt(2)" ::: "memory");
  __builtin_amdgcn_s_barrier();
  __builtin_amdgcn_sched_barrier(0);

#pragma unroll 1
  for (int g = 0; g < 64; ++g) {
    int cc = g & 1, nb = cc ^ 1;
    int l0 = (g >> 3) * 256;
    int l0n = ((g + 1) >> 3) * 256;
    int kbn = ((g + 1) & 7) * 64;
    bf16x8 aF[4], bF[4];
    // ---- phase A: Q(ks0, mh0); stage SA0(g+1)
    RD_A(0, 0, cc);
    RD_B(0, cc);
    if (g < 63) SA_(nb, 0, l0n, kbn);
    MMQ(0);
    if (g < 63)
      asm volatile("s_waitcnt vmcnt(2)" ::: "memory");  // SA1(g) landed
    else
      asm volatile("s_waitcnt vmcnt(0)" ::: "memory");
    __builtin_amdgcn_s_barrier();
    __builtin_amdgcn_sched_barrier(0);
    // ---- phase B: Q(ks0,mh1), Q(ks1,mh0), Q(ks1,mh1); stage SB0,SB1,SA1
    RD_A(1, 0, cc);
    if (g < 63) SB_(nb, 0, kbn);
    MMQ(1);
    RD_A(0, 1, cc);
    RD_B(1, cc);
    if (g < 63) SB_(nb, 1, kbn);
    MMQ(0);
    RD_A(1, 1, cc);
    if (g < 63) SA_(nb, 1, l0n, kbn);
    MMQ(1);
    asm volatile("s_waitcnt lgkmcnt(0)" ::: "memory");
    asm volatile("s_waitcnt vmcnt(2)" ::: "memory");  // SA0/SB0/SB1(g+1) in
    __builtin_amdgcn_s_barrier();
    __builtin_amdgcn_sched_barrier(0);
    // ---- item epilogue every 8 tiles (K complete for these 256 l-rows)
    if ((g & 7) == 7) {
      float part[32];
#pragma unroll
      for (int m = 0; m < 8; ++m)
#pragma unroll
        for (int j = 0; j < 4; ++j) {
          float s = 0.f;
#pragma unroll
          for (int n = 0; n < 4; ++n) s += fast_tanh2(acc[m][n][j]) * vv[n];
          part[m * 4 + j] = s;
        }
#pragma unroll
      for (int p = 0; p < 32; ++p) {
        float v = part[p];
        v += __shfl_xor(v, 1, 64);
        v += __shfl_xor(v, 2, 64);
        v += __shfl_xor(v, 4, 64);
        v += __shfl_xor(v, 8, 64);
        part[p] = v;
      }
      __syncthreads();
      if (rl == 0) {
#pragma unroll
        for (int m = 0; m < 8; ++m)
#pragma unroll
          for (int j = 0; j < 4; ++j)
            redsm[wc][wr * 128 + m * 16 + q * 4 + j] = part[m * 4 + j];
      }
      __syncthreads();
      if (tid < 256) {
        float s = redsm[0][tid] + redsm[1][tid] + redsm[2][tid] +
                  redsm[3][tid];
        pscore[((size_t)ut * B_ * H_ + b * H_ + h) * L_ + l0 + tid] = s;
      }
      // re-init acc for the next item
#pragma unroll
      for (int m = 0; m < 8; ++m)
#pragma unroll
        for (int n = 0; n < 4; ++n)
#pragma unroll
          for (int j = 0; j < 4; ++j) acc[m][n][j] = cu[n];
    }
  }
#undef SA_
#undef SB_
#undef RD_A
#undef RD_B
#undef MMQ
}

// ---------------------------------------------------------------------------
// softmax over L per (b,h): sums the 2 u-slice partials (bV omitted --
// uniform over L, cancels); writes attn (aliases pscore slice 0; row is
// LDS-cached first) + aw_out [B,L,H,1].
// ---------------------------------------------------------------------------
__global__ __launch_bounds__(256) void softmax_kernel(
    const float* __restrict__ pscore, float* __restrict__ attn,
    float* __restrict__ aw_out) {
  int bh = blockIdx.x;
  int b = bh / H_, h = bh % H_;
  const float* p0 = pscore + (size_t)bh * L_;
  const float* p1 = pscore + ((size_t)B_ * H_ + bh) * L_;
  __shared__ float sv[L_];  // 8 KB
  __shared__ float red[256];

  for (int i = threadIdx.x; i < L_ / 4; i += 256) {
    float4 a = ((const float4*)p0)[i];
    float4 c = ((const float4*)p1)[i];
    a.x += c.x; a.y += c.y; a.z += c.z; a.w += c.w;
    ((float4*)sv)[i] = a;
  }
  __syncthreads();

  float m = -1e30f;
  for (int l = threadIdx.x; l < L_; l += 256) m = fmaxf(m, sv[l]);
  red[threadIdx.x] = m;
  __syncthreads();
  for (int st = 128; st > 0; st >>= 1) {
    if (threadIdx.x < st)
      red[threadIdx.x] = fmaxf(red[threadIdx.x], red[threadIdx.x + st]);
    __syncthreads();
  }
  m = red[0];
  __syncthreads();

  float sum = 0.f;
  for (int l = threadIdx.x; l < L_; l += 256) sum += __expf(sv[l] - m);
  red[threadIdx.x] = sum;
  __syncthreads();
  for (int st = 128; st > 0; st >>= 1) {
    if (threadIdx.x < st) red[threadIdx.x] += red[threadIdx.x + st];
    __syncthreads();
  }
  float inv = 1.f / red[0];

  for (int l = threadIdx.x; l < L_; l += 256) {
    float a = __expf(sv[l] - m) * inv;
    attn[(size_t)bh * L_ + l] = a;
    aw_out[((size_t)b * L_ + l) * H_ + h] = a;
  }
}

// ---------------------------------------------------------------------------
// context split-L: partial[lz][b,h,d] = sum_{l in chunk lz} attn*F(bf16)
// ---------------------------------------------------------------------------
__global__ __launch_bounds__(256) void context_part_kernel(
    const u16* __restrict__ Abf, const float* __restrict__ attn,
    float* __restrict__ partial) {
  int b = blockIdx.x;
  int d0 = blockIdx.y * 64;
  int lz = blockIdx.z;
  int td = threadIdx.x & 63;
  int tl = threadIdx.x >> 6;  // 0..3

  __shared__ float as[H_][256];  // 8 KB
  for (int idx = threadIdx.x; idx < H_ * 256; idx += 256)
    as[idx >> 8][idx & 255] =
        attn[((size_t)b * H_ + (idx >> 8)) * L_ + lz * 256 + (idx & 255)];
  __syncthreads();

  float acc[H_] = {};
  for (int l = tl; l < 256; l += 4) {
    float f = bf2f(Abf[((size_t)b * L_ + lz * 256 + l) * DF + d0 + td]);
#pragma unroll
    for (int h = 0; h < H_; h++) acc[h] += as[h][l] * f;
  }

  __shared__ float red[4][H_][64];  // 8 KB
#pragma unroll
  for (int h = 0; h < H_; h++) red[tl][h][td] = acc[h];
  __syncthreads();
  if (tl == 0) {
#pragma unroll
    for (int h = 0; h < H_; h++) {
      float v = red[0][h][td] + red[1][h][td] + red[2][h][td] + red[3][h][td];
      partial[(size_t)lz * B_ * H_ * DF + ((size_t)b * H_ + h) * DF + d0 + td] =
          v;
    }
  }
}

__global__ __launch_bounds__(256) void context_combine_kernel(
    const float* __restrict__ partial, float* __restrict__ ctx_out) {
  int i = blockIdx.x * 256 + threadIdx.x;  // over B*H*DF
  float s = 0.f;
#pragma unroll
  for (int z = 0; z < 8; z++) s += partial[(size_t)z * B_ * H_ * DF + i];
  ctx_out[i] = s;
}

// ---------------------------------------------------------------------------
extern "C" void kernel_launch(void* const* d_in, const int* in_sizes, int n_in,
                              void* d_out, int out_size, void* d_ws,
                              size_t ws_size, hipStream_t stream) {
  const float* features = (const float*)d_in[0];  // [B,L,Df]
  const float* hidden   = (const float*)d_in[1];  // [B,H,Dh]
  const float* W1       = (const float*)d_in[2];  // [H,Df,U]
  const float* b1       = (const float*)d_in[3];  // [H,U]
  const float* W2       = (const float*)d_in[4];  // [H,Dh,U]
  const float* b2       = (const float*)d_in[5];  // [H,U]
  const float* V        = (const float*)d_in[6];  // [H,U]
  // d_in[7] = bV: uniform over L per (b,h) -> cancels in softmax; unused.

  float* out = (float*)d_out;
  float* ctx_out = out;                 // [B,H,Df]
  float* aw_out  = out + B_ * H_ * DF;  // [B,L,H,1]

  // ws layout (floats): c | pscore[2 slices] | cpart, then bf16: Abf | W1T
  //  - hproj partials (524288 f) alias pscore (524288 f): consumed by
  //    hproj_combine before score writes pscore.
  //  - attn aliases pscore slice 0 (softmax LDS-caches the row first).
  float* c_buf  = (float*)d_ws;
  float* pscore = c_buf + (size_t)B_ * H_ * U_;
  float* attn   = pscore;  // alias (see above)
  float* hpart  = pscore;  // alias (see above)
  float* cpart  = pscore + (size_t)2 * B_ * H_ * L_;  // 8*B*H*DF floats
  u16* Abf = (u16*)(cpart + (size_t)8 * B_ * H_ * DF);
  u16* W1T = Abf + (size_t)B_ * L_ * DF;

  prep_kernel<<<16384 + 2048 + 128, 256, 0, stream>>>(features, Abf, W1, W1T,
                                                      hidden, W2, hpart);
  hproj_combine_kernel<<<(B_ * H_ * U_) / 256, 256, 0, stream>>>(hpart, b1, b2,
                                                                 c_buf);
  score_kernel<<<256, 512, 0, stream>>>(Abf, W1T, c_buf, V, pscore);
  softmax_kernel<<<B_ * H_, 256, 0, stream>>>(pscore, attn, aw_out);
  context_part_kernel<<<dim3(B_, DF / 64, 8), 256, 0, stream>>>(Abf, attn,
                                                                cpart);
  context_combine_kernel<<<(B_ * H_ * DF) / 256, 256, 0, stream>>>(cpart,
                                                                   ctx_out);
}